// Round 5
// baseline (447.907 us; speedup 1.0000x reference)
//
#include <hip/hip_runtime.h>

// Causal MHA forward, B=4 S=2048 H=16 D=128, fp32 BSHD in/out.
// R8 = R5 (best simple structure, VGPR=104) with __launch_bounds__(256,4).
// R7 post-mortem: asm-prefetch staging regs got SPILLED (VGPR stayed 124,
// FETCH +42MB scratch, dur 243us) -> revert. R3/R5/R6/R7 all pin ~204us with
// OccupancyPercent ~21% == the (256,2) residency cap (8/32 waves). This round
// pulls the TLP lever instead of ILP: 4 blocks/CU (VGPR 104<=128, LDS 4x32KB
// =128KB<=160KB). Latency per block now hides under 3 other resident blocks.
// Block = 4 waves x 32 q = 128 q-rows; BK=64 key tiles.

typedef short bf16x8 __attribute__((ext_vector_type(8)));
typedef float f32x16 __attribute__((ext_vector_type(16)));
typedef unsigned u32x4 __attribute__((ext_vector_type(4)));

#define SEQ 2048
#define NH  16
#define HD  128
#define BQ  128
#define BK  64

// pack 2 fp32 -> bf16 pair (round-half-up: <=1ulp vs RNE, ~2.5 VALU ops)
__device__ __forceinline__ unsigned pkbf(float a, float b) {
  unsigned ua = __builtin_bit_cast(unsigned, a);
  unsigned ub = __builtin_bit_cast(unsigned, b);
  return ((ua + 0x8000u) >> 16) | ((ub + 0x8000u) & 0xFFFF0000u);
}

__global__ __launch_bounds__(256, 4) void fa_fwd(
    const float* __restrict__ Qg, const float* __restrict__ Kg,
    const float* __restrict__ Vg, float* __restrict__ Og)
{
  // K:  [key 64][d 128] bf16, 256B rows, byte-col ^ ((row&7)<<4)   (16 KB)
  // V^T:[d 128][key 64] bf16, 128B rows, byte-col ^ ((d&7)<<4)     (16 KB)
  __shared__ __align__(16) short Klds[BK * HD];
  __shared__ __align__(16) short Vtlds[HD * BK];

  const float qscale = 0.08838834764831845f * 1.4426950408889634f; // 1/sqrt(D)*log2e
  const int tid  = threadIdx.x;
  const int w    = tid >> 6;         // wave 0..3
  const int lane = tid & 63;
  const int col  = lane & 31;        // q column / A-operand m-row
  const int hi   = lane >> 5;
  const int hi16 = hi << 4;

  const int bh = (int)blockIdx.x & 63;          // bh fast: spreads across XCDs
  const int qi = 15 - ((int)blockIdx.x >> 6);   // heavy q-tiles first
  const int bb = bh >> 4;
  const int hh = bh & 15;
  const int q0  = qi << 7;
  const int q0w = q0 + w * 32;                  // this wave's 32 q-rows
  const int myq = q0w + col;

  // ---- Q fragments (B-operand, pre-scaled): Q[myq][16ks + 8hi + j] ----
  const float* qp = Qg + ((bb * SEQ + myq) * NH + hh) * HD;
  bf16x8 bq[8];
#pragma unroll
  for (int ks = 0; ks < 8; ++ks) {
    const float4 a = *(const float4*)(qp + ks * 16 + hi * 8);
    const float4 b = *(const float4*)(qp + ks * 16 + hi * 8 + 4);
    u32x4 t;
    t[0] = pkbf(a.x * qscale, a.y * qscale);
    t[1] = pkbf(a.z * qscale, a.w * qscale);
    t[2] = pkbf(b.x * qscale, b.y * qscale);
    t[3] = pkbf(b.z * qscale, b.w * qscale);
    bq[ks] = __builtin_bit_cast(bf16x8, t);
  }

  // O^T[d = 32*mt + (reg&3) + 8*(reg>>2) + 4*hi][q = col]
  f32x16 O[4] = {};
  float m_r = -1e30f, l_r = 0.f;

  // staging assignments (256 threads)
  const int krow = tid >> 2;            // 0..63, 4 threads/row
  const int kd0  = (tid & 3) << 5;      // 0,32,64,96
  const int vkp  = tid & 31;            // key pair
  const int vd0  = (tid >> 5) << 4;     // 0,16,..,112
  const unsigned swz = (unsigned)((col & 7) << 4);  // frag-read swizzle (row&7 == col&7)

  for (int kv0 = 0; kv0 < q0 + BQ; kv0 += BK) {
    // ---- stage K tile ----
    {
      const float* kr = Kg + ((bb * SEQ + kv0 + krow) * NH + hh) * HD + kd0;
      char* kb = (char*)Klds + krow * 256;
      const unsigned sw = (unsigned)((krow & 7) << 4);
#pragma unroll
      for (int i = 0; i < 4; ++i) {
        const float4 x = *(const float4*)(kr + i * 8);
        const float4 y = *(const float4*)(kr + i * 8 + 4);
        u32x4 t;
        t[0] = pkbf(x.x, x.y); t[1] = pkbf(x.z, x.w);
        t[2] = pkbf(y.x, y.y); t[3] = pkbf(y.z, y.w);
        *(u32x4*)(kb + (((unsigned)(kd0 * 2 + i * 16)) ^ sw)) = t;
      }
    }
    // ---- stage V transposed ----
    {
      const float* vr = Vg + ((bb * SEQ + kv0 + 2 * vkp) * NH + hh) * HD + vd0;
#pragma unroll
      for (int i2 = 0; i2 < 4; ++i2) {
        const float4 v0 = *(const float4*)(vr + i2 * 4);
        const float4 v1 = *(const float4*)(vr + NH * HD + i2 * 4);
        const float f0[4] = {v0.x, v0.y, v0.z, v0.w};
        const float f1[4] = {v1.x, v1.y, v1.z, v1.w};
#pragma unroll
        for (int j = 0; j < 4; ++j) {
          const int d = vd0 + i2 * 4 + j;
          *(unsigned*)((char*)Vtlds + d * 128 +
                       (((unsigned)(vkp * 4)) ^ ((unsigned)((d & 7) << 4)))) =
              pkbf(f0[j], f1[j]);
        }
      }
    }
    __syncthreads();

    if (kv0 <= q0w + 31) {   // wave-uniform: wave has q-rows >= kv0
      // ---- S^T = K * Q^T, C-layout: st[mt][reg] = S[key][q=col] ----
      f32x16 st[2] = {};
#pragma unroll
      for (int ks = 0; ks < 8; ++ks) {
#pragma unroll
        for (int mt = 0; mt < 2; ++mt) {
          const bf16x8 ka = *(const bf16x8*)((const char*)Klds + (mt * 32 + col) * 256 +
                                             (((unsigned)(ks * 32 + hi16)) ^ swz));
          st[mt] = __builtin_amdgcn_mfma_f32_32x32x16_bf16(ka, bq[ks], st[mt], 0, 0, 0);
        }
      }
      // ---- causal mask (at most one crossing tile per wave) ----
      if (kv0 + BK - 1 > q0w) {
#pragma unroll
        for (int mt = 0; mt < 2; ++mt)
#pragma unroll
          for (int r = 0; r < 16; ++r) {
            const int key = kv0 + mt * 32 + (r & 3) + 8 * (r >> 2) + 4 * hi;
            if (key > myq) st[mt][r] = -1e30f;
          }
      }
      // ---- online softmax: 31 in-lane fmax + 1 cross-half xor ----
      float pmax = st[0][0];
#pragma unroll
      for (int mt = 0; mt < 2; ++mt)
#pragma unroll
        for (int r = 0; r < 16; ++r) pmax = fmaxf(pmax, st[mt][r]);
      pmax = fmaxf(pmax, __shfl_xor(pmax, 32));
      // defer-max (T13): skip rescale unless some lane would exceed 2^8
      if (!__all(pmax - m_r <= 8.f)) {
        const float mn = fmaxf(m_r, pmax);
        const float al = __builtin_amdgcn_exp2f(m_r - mn);
        m_r = mn;
        l_r *= al;
#pragma unroll
        for (int mt = 0; mt < 4; ++mt)
#pragma unroll
          for (int r = 0; r < 16; ++r) O[mt][r] *= al;
      }
      // ---- exp + row-sum + pack P to bf16 (group g = 4*mt + s) ----
      unsigned dA[8], dB[8];
      float rs = 0.f;
#pragma unroll
      for (int g = 0; g < 8; ++g) {
        const int mt = g >> 2, s = g & 3;
        const float p0 = __builtin_amdgcn_exp2f(st[mt][4 * s + 0] - m_r);
        const float p1 = __builtin_amdgcn_exp2f(st[mt][4 * s + 1] - m_r);
        const float p2 = __builtin_amdgcn_exp2f(st[mt][4 * s + 2] - m_r);
        const float p3 = __builtin_amdgcn_exp2f(st[mt][4 * s + 3] - m_r);
        rs += (p0 + p1) + (p2 + p3);
        dA[g] = pkbf(p0, p1);
        dB[g] = pkbf(p2, p3);
      }
      rs += __shfl_xor(rs, 32);
      l_r += rs;
      // ---- PV: O^T += V^T * P^T; P^T B-frag via permlane32_swap (T12) ----
      // k-step t (keys 16t..16t+15): frag dwords = {lo.dA(g), lo.dB(g),
      // hi.dA(g), hi.dB(g)} with g = hi_dst + 2t  ==  swap(d[2t], d[2t+1]).
#pragma unroll
      for (int t = 0; t < 4; ++t) {
        const auto ra = __builtin_amdgcn_permlane32_swap(dA[2 * t], dA[2 * t + 1], false, false);
        const auto rb = __builtin_amdgcn_permlane32_swap(dB[2 * t], dB[2 * t + 1], false, false);
        u32x4 pf;
        pf[0] = (unsigned)ra[0]; pf[1] = (unsigned)rb[0];
        pf[2] = (unsigned)ra[1]; pf[3] = (unsigned)rb[1];
        const bf16x8 pb = __builtin_bit_cast(bf16x8, pf);
#pragma unroll
        for (int mt = 0; mt < 4; ++mt) {
          const bf16x8 va = *(const bf16x8*)((const char*)Vtlds + (mt * 32 + col) * 128 +
                                             (((unsigned)(t * 32 + hi16)) ^ swz));
          O[mt] = __builtin_amdgcn_mfma_f32_32x32x16_bf16(va, pb, O[mt], 0, 0, 0);
        }
      }
    }
    __syncthreads();
  }

  // ---- epilogue: O^T[d][q=col] -> row myq, float4 per (mt, s) ----
  const float inv = 1.0f / l_r;
  float* op = Og + ((bb * SEQ + myq) * NH + hh) * HD;
#pragma unroll
  for (int mt = 0; mt < 4; ++mt)
#pragma unroll
    for (int s = 0; s < 4; ++s) {
      float4 ov;
      ov.x = O[mt][4 * s + 0] * inv;
      ov.y = O[mt][4 * s + 1] * inv;
      ov.z = O[mt][4 * s + 2] * inv;
      ov.w = O[mt][4 * s + 3] * inv;
      *(float4*)(op + mt * 32 + s * 8 + hi * 4) = ov;
    }
}

extern "C" void kernel_launch(void* const* d_in, const int* in_sizes, int n_in,
                              void* d_out, int out_size, void* d_ws, size_t ws_size,
                              hipStream_t stream) {
  const float* q = (const float*)d_in[0];
  const float* k = (const float*)d_in[1];
  const float* v = (const float*)d_in[2];
  float* o = (float*)d_out;
  dim3 grid(64 * (SEQ / BQ));   // 64 (b,h) x 16 q-tiles = 1024 blocks
  dim3 block(256);
  fa_fwd<<<grid, block, 0, stream>>>(q, k, v, o);
}

// Round 7
// 290.235 us; speedup vs baseline: 1.5433x; 1.5433x over previous
//
#include <hip/hip_runtime.h>

// Causal MHA forward, B=4 S=2048 H=16 D=128, fp32 BSHD in/out.
// R10 = R9 resubmit (round 6 bench was an infra failure, kernel never ran).
// R9: m214-geometry port. 8 waves x 32q (BQ=256), BK=64, double-buffered
// bf16 K/V LDS (64KB), async-STAGE split (T14): 8 asm global_load_dwordx4
// per thread issued BEFORE compute (32 VGPR in flight - small enough not to
// spill, unlike R7's 64), vmcnt(0)+convert+ds_write to the OTHER buffer after
// compute, one barrier per tile. R8 post-mortem: (256,4) forced VGPR=64 ->
// O-accumulator spilled (FETCH +240MB, 331us). R7: 64 staging VGPR spilled.
// BQ=256 also halves staging cost + K/V global re-reads per FLOP.
// Grid 512 blocks, qi descending -> CU pairing 32+4, 28+8 = 36 slots each.

typedef short bf16x8 __attribute__((ext_vector_type(8)));
typedef float f32x16 __attribute__((ext_vector_type(16)));
typedef unsigned u32x4 __attribute__((ext_vector_type(4)));

#define SEQ 2048
#define NH  16
#define HD  128
#define BQ  256
#define BK  64

// pack 2 fp32 -> bf16 pair (round-half-up: <=1ulp vs RNE, ~2.5 VALU ops)
__device__ __forceinline__ unsigned pkbf(float a, float b) {
  unsigned ua = __builtin_bit_cast(unsigned, a);
  unsigned ub = __builtin_bit_cast(unsigned, b);
  return ((ua + 0x8000u) >> 16) | ((ub + 0x8000u) & 0xFFFF0000u);
}

// un-sinkable 16B global load (volatile asm; no waitcnt -- caller waits)
__device__ __forceinline__ float4 gld16(const float* p) {
  float4 d;
  asm volatile("global_load_dwordx4 %0, %1, off" : "=v"(d) : "v"(p));
  return d;
}

__global__ __launch_bounds__(512, 2) void fa_fwd(
    const float* __restrict__ Qg, const float* __restrict__ Kg,
    const float* __restrict__ Vg, float* __restrict__ Og)
{
  // K:  [key 64][d 128] bf16, 256B rows, byte-col ^ ((row&7)<<4)   (16 KB x2)
  // V^T:[d 128][key 64] bf16, 128B rows, byte-col ^ ((d&7)<<4)     (16 KB x2)
  __shared__ __align__(16) short KldsA[BK * HD], KldsB[BK * HD];
  __shared__ __align__(16) short VtldsA[HD * BK], VtldsB[HD * BK];

  const float qscale = 0.08838834764831845f * 1.4426950408889634f; // 1/sqrt(D)*log2e
  const int tid  = threadIdx.x;
  const int w    = tid >> 6;         // wave 0..7
  const int lane = tid & 63;
  const int col  = lane & 31;        // q column / A-operand m-row
  const int hi   = lane >> 5;
  const int hi16 = hi << 4;

  const int bh = (int)blockIdx.x & 63;          // bh fast: spreads across XCDs
  const int qi = 7 - ((int)blockIdx.x >> 6);    // heavy q-tiles first
  const int bb = bh >> 4;
  const int hh = bh & 15;
  const int q0  = qi << 8;
  const int q0w = q0 + w * 32;                  // this wave's 32 q-rows
  const int myq = q0w + col;

  // ---- Q fragments (B-operand, pre-scaled): Q[myq][16ks + 8hi + j] ----
  const float* qp = Qg + ((bb * SEQ + myq) * NH + hh) * HD;
  bf16x8 bq[8];
#pragma unroll
  for (int ks = 0; ks < 8; ++ks) {
    const float4 a = *(const float4*)(qp + ks * 16 + hi * 8);
    const float4 b = *(const float4*)(qp + ks * 16 + hi * 8 + 4);
    u32x4 t;
    t[0] = pkbf(a.x * qscale, a.y * qscale);
    t[1] = pkbf(a.z * qscale, a.w * qscale);
    t[2] = pkbf(b.x * qscale, b.y * qscale);
    t[3] = pkbf(b.z * qscale, b.w * qscale);
    bq[ks] = __builtin_bit_cast(bf16x8, t);
  }

  // O^T[d = 32*mt + (reg&3) + 8*(reg>>2) + 4*hi][q = col]
  f32x16 O[4] = {};
  float m_r = -1e30f, l_r = 0.f;

  // staging assignments (512 threads)
  const int krow = tid >> 3;            // 0..63, 8 threads/row
  const int kd0  = (tid & 7) << 4;      // 0,16,..,112 (16 floats)
  const int vkp  = tid & 31;            // keys 2vkp, 2vkp+1
  const int vd0  = (tid >> 5) << 3;     // 0,8,..,120 (8 floats)
  const unsigned swz = (unsigned)((col & 7) << 4);  // frag-read swizzle

  const float* Kb = Kg + ((long)(bb * SEQ) * NH + hh) * HD;
  const float* Vb = Vg + ((long)(bb * SEQ) * NH + hh) * HD;

  // in-flight staging (named scalars: 8 float4 = 32 VGPR)
  float4 ks0, ks1, ks2, ks3, va0, va1, vb0, vb1;

  // ---- issue global loads for tile kv via volatile asm (no waits) ----
  auto ISSUE = [&](int kv) {
    const float* kr = Kb + (long)(kv + krow) * (NH * HD) + kd0;
    ks0 = gld16(kr);     ks1 = gld16(kr + 4);
    ks2 = gld16(kr + 8); ks3 = gld16(kr + 12);
    const float* vr = Vb + (long)(kv + 2 * vkp) * (NH * HD) + vd0;
    va0 = gld16(vr);            va1 = gld16(vr + 4);
    vb0 = gld16(vr + NH * HD);  vb1 = gld16(vr + NH * HD + 4);
  };

  // ---- convert + write staged regs -> LDS (swizzled), explicit targets ----
  auto WRITET = [&](short* kdst, short* vdst) {
    char* kb = (char*)kdst + krow * 256;
    const unsigned sw = (unsigned)((krow & 7) << 4);
    u32x4 t0, t1;
    t0[0] = pkbf(ks0.x, ks0.y); t0[1] = pkbf(ks0.z, ks0.w);
    t0[2] = pkbf(ks1.x, ks1.y); t0[3] = pkbf(ks1.z, ks1.w);
    t1[0] = pkbf(ks2.x, ks2.y); t1[1] = pkbf(ks2.z, ks2.w);
    t1[2] = pkbf(ks3.x, ks3.y); t1[3] = pkbf(ks3.z, ks3.w);
    *(u32x4*)(kb + (((unsigned)(kd0 * 2)) ^ sw))      = t0;
    *(u32x4*)(kb + (((unsigned)(kd0 * 2 + 16)) ^ sw)) = t1;
    const float a[8] = {va0.x, va0.y, va0.z, va0.w, va1.x, va1.y, va1.z, va1.w};
    const float b[8] = {vb0.x, vb0.y, vb0.z, vb0.w, vb1.x, vb1.y, vb1.z, vb1.w};
#pragma unroll
    for (int j = 0; j < 8; ++j) {
      const int d = vd0 + j;
      *(unsigned*)((char*)vdst + d * 128 +
                   (((unsigned)(vkp * 4)) ^ ((unsigned)((d & 7) << 4)))) =
          pkbf(a[j], b[j]);
    }
  };

  const int nt = (q0 + BQ) / BK;

  short *kcur = KldsA, *knxt = KldsB;
  short *vcur = VtldsA, *vnxt = VtldsB;

  // prologue: stage tile 0 into cur
  ISSUE(0);
  asm volatile("s_waitcnt vmcnt(0)" ::: "memory");
  __builtin_amdgcn_sched_barrier(0);
  WRITET(kcur, vcur);
  __syncthreads();

  for (int it = 0; it < nt; ++it) {
    const int kv0 = it * BK;
    if (it + 1 < nt) ISSUE(kv0 + BK);   // fire next tile's loads (T14)

    if (kv0 <= q0w + 31) {   // wave-uniform: wave has q-rows >= kv0
      // ---- S^T = K * Q^T, C-layout: st[mt][reg] = S[key][q=col] ----
      f32x16 st[2] = {};
      __builtin_amdgcn_s_setprio(1);
#pragma unroll
      for (int ks = 0; ks < 8; ++ks) {
#pragma unroll
        for (int mt = 0; mt < 2; ++mt) {
          const bf16x8 ka = *(const bf16x8*)((const char*)kcur + (mt * 32 + col) * 256 +
                                             (((unsigned)(ks * 32 + hi16)) ^ swz));
          st[mt] = __builtin_amdgcn_mfma_f32_32x32x16_bf16(ka, bq[ks], st[mt], 0, 0, 0);
        }
      }
      __builtin_amdgcn_s_setprio(0);
      // ---- causal mask (at most one crossing tile per wave) ----
      if (kv0 + BK - 1 > q0w) {
#pragma unroll
        for (int mt = 0; mt < 2; ++mt)
#pragma unroll
          for (int r = 0; r < 16; ++r) {
            const int key = kv0 + mt * 32 + (r & 3) + 8 * (r >> 2) + 4 * hi;
            if (key > myq) st[mt][r] = -1e30f;
          }
      }
      // ---- online softmax: 31 in-lane fmax + 1 cross-half xor ----
      float pmax = st[0][0];
#pragma unroll
      for (int mt = 0; mt < 2; ++mt)
#pragma unroll
        for (int r = 0; r < 16; ++r) pmax = fmaxf(pmax, st[mt][r]);
      pmax = fmaxf(pmax, __shfl_xor(pmax, 32));
      // defer-max (T13): skip rescale unless some lane would exceed 2^8
      if (!__all(pmax - m_r <= 8.f)) {
        const float mn = fmaxf(m_r, pmax);
        const float al = __builtin_amdgcn_exp2f(m_r - mn);
        m_r = mn;
        l_r *= al;
#pragma unroll
        for (int mt = 0; mt < 4; ++mt)
#pragma unroll
          for (int r = 0; r < 16; ++r) O[mt][r] *= al;
      }
      // ---- exp + row-sum + pack P to bf16 (group g = 4*mt + s) ----
      unsigned dA[8], dB[8];
      float rs = 0.f;
#pragma unroll
      for (int g = 0; g < 8; ++g) {
        const int mt = g >> 2, s = g & 3;
        const float p0 = __builtin_amdgcn_exp2f(st[mt][4 * s + 0] - m_r);
        const float p1 = __builtin_amdgcn_exp2f(st[mt][4 * s + 1] - m_r);
        const float p2 = __builtin_amdgcn_exp2f(st[mt][4 * s + 2] - m_r);
        const float p3 = __builtin_amdgcn_exp2f(st[mt][4 * s + 3] - m_r);
        rs += (p0 + p1) + (p2 + p3);
        dA[g] = pkbf(p0, p1);
        dB[g] = pkbf(p2, p3);
      }
      rs += __shfl_xor(rs, 32);
      l_r += rs;
      // ---- PV: O^T += V^T * P^T; P^T B-frag via permlane32_swap (T12) ----
      // k-step t (keys 16t..16t+15): frag dwords = {lo.dA(g), lo.dB(g),
      // hi.dA(g), hi.dB(g)} with g = hi_dst + 2t  ==  swap(d[2t], d[2t+1]).
      __builtin_amdgcn_s_setprio(1);
#pragma unroll
      for (int t = 0; t < 4; ++t) {
        const auto ra = __builtin_amdgcn_permlane32_swap(dA[2 * t], dA[2 * t + 1], false, false);
        const auto rb = __builtin_amdgcn_permlane32_swap(dB[2 * t], dB[2 * t + 1], false, false);
        u32x4 pf;
        pf[0] = (unsigned)ra[0]; pf[1] = (unsigned)rb[0];
        pf[2] = (unsigned)ra[1]; pf[3] = (unsigned)rb[1];
        const bf16x8 pb = __builtin_bit_cast(bf16x8, pf);
#pragma unroll
        for (int mt = 0; mt < 4; ++mt) {
          const bf16x8 va = *(const bf16x8*)((const char*)vcur + (mt * 32 + col) * 128 +
                                             (((unsigned)(t * 32 + hi16)) ^ swz));
          O[mt] = __builtin_amdgcn_mfma_f32_32x32x16_bf16(va, pb, O[mt], 0, 0, 0);
        }
      }
      __builtin_amdgcn_s_setprio(0);
    }

    if (it + 1 < nt) {   // block-uniform: wait prefetch, write OTHER buffer
      asm volatile("s_waitcnt vmcnt(0)" ::: "memory");
      __builtin_amdgcn_sched_barrier(0);
      WRITET(knxt, vnxt);
    }
    __syncthreads();     // one barrier/tile: publishes knxt, retires kcur reads
    short* t0 = kcur; kcur = knxt; knxt = t0;
    short* t1 = vcur; vcur = vnxt; vnxt = t1;
  }

  // ---- epilogue: O^T[d][q=col] -> row myq, float4 per (mt, s) ----
  const float inv = 1.0f / l_r;
  float* op = Og + ((bb * SEQ + myq) * NH + hh) * HD;
#pragma unroll
  for (int mt = 0; mt < 4; ++mt)
#pragma unroll
    for (int s = 0; s < 4; ++s) {
      float4 ov;
      ov.x = O[mt][4 * s + 0] * inv;
      ov.y = O[mt][4 * s + 1] * inv;
      ov.z = O[mt][4 * s + 2] * inv;
      ov.w = O[mt][4 * s + 3] * inv;
      *(float4*)(op + mt * 32 + s * 8 + hi * 4) = ov;
    }
}

extern "C" void kernel_launch(void* const* d_in, const int* in_sizes, int n_in,
                              void* d_out, int out_size, void* d_ws, size_t ws_size,
                              hipStream_t stream) {
  const float* q = (const float*)d_in[0];
  const float* k = (const float*)d_in[1];
  const float* v = (const float*)d_in[2];
  float* o = (float*)d_out;
  dim3 grid(64 * (SEQ / BQ));   // 64 (b,h) x 8 q-tiles = 512 blocks
  dim3 block(512);
  fa_fwd<<<grid, block, 0, stream>>>(q, k, v, o);
}